// Round 14
// baseline (475.292 us; speedup 1.0000x reference)
//
#include <hip/hip_runtime.h>
#include <hip/hip_bf16.h>

// GCN 3-layer fused pipeline for MI355X.
// Â(xW) == (Âx)W ; CSR built per call; BN+ReLU as separate in-place pass.
// R14: agg+GEMM fused (agg block's 16 rows -> LDS tile -> MFMA in-block;
//      T1 global round-trip eliminated); stage packed to 4B/entry.

#define FD 64
#define EPSF 1e-5f

#define NBUCK 256        // max buckets (bucket = dst >> BSHIFT)
#define BSHIFT 9
#define BWID 512         // nodes per bucket (pow2); supports N <= 131072
#define SLOTS 28         // LDS slots per bucket in fill1
#define P1_EDGES 4096
#define RPMASK 0x3FFFFF  // rowptr start mask (22 bits); deg in bits 22..31
#define SMASK 0x1FFFF    // packed stage: src in 17 bits, dlocal in bits 17..25

typedef __attribute__((ext_vector_type(8))) short bf16x8;
typedef __attribute__((ext_vector_type(4))) float f32x4;

__device__ __forceinline__ ushort f2bf_bits(float f) {
  __hip_bfloat16 h = __float2bfloat16(f);
  return *(ushort*)&h;
}
__device__ __forceinline__ unsigned packbf(float lo, float hi) {
  return (unsigned)f2bf_bits(lo) | ((unsigned)f2bf_bits(hi) << 16);
}

// ---------------- init: bcur = b*cap, zero stats ----------------
__global__ __launch_bounds__(256) void init_kernel(int* __restrict__ bcur,
                                                   float* __restrict__ stats1,
                                                   float* __restrict__ stats2,
                                                   int nB, int cap) {
  int t = threadIdx.x;
  if (t < nB) bcur[t] = t * cap;
  if (t < 128) {
    stats1[t] = 0.f;
    stats2[t] = 0.f;
  }
}

// ---------------- phase-1 fill: LDS-binned staging, packed 4B entries --------
__global__ __launch_bounds__(256) void fill1_kernel(const int* __restrict__ ei, int E,
                                                    int* __restrict__ bcur,
                                                    int* __restrict__ stage) {
  __shared__ int sbuf[NBUCK][SLOTS];
  __shared__ int scnt[NBUCK];
  __shared__ int sbase[NBUCK];
  __shared__ int s_is64;
  const int tid = threadIdx.x;
  scnt[tid] = 0;
  if (tid < 64) {
    int v = ei[2 * tid + 1];
    unsigned long long nz = __ballot(v != 0);
    if (tid == 0) s_is64 = (nz == 0ull) ? 1 : 0;
  }
  __syncthreads();
  const int is64 = s_is64;
  const int base = blockIdx.x * P1_EDGES;
#pragma unroll 1
  for (int k = 0; k < P1_EDGES / 256; ++k) {
    int e = base + k * 256 + tid;
    if (e < E) {
      int s = is64 ? ei[2 * e] : ei[e];
      int d = is64 ? ei[2 * (E + e)] : ei[E + e];
      int b = d >> BSHIFT;
      int pk = s | ((d & (BWID - 1)) << 17);
      int pos = atomicAdd(&scnt[b], 1);
      if (pos < SLOTS) {
        sbuf[b][pos] = pk;
      } else {
        stage[atomicAdd(&bcur[b], 1)] = pk;  // rare overflow
      }
    }
  }
  __syncthreads();
  {
    int c = scnt[tid];
    if (c > SLOTS) c = SLOTS;
    scnt[tid] = c;
    sbase[tid] = c ? atomicAdd(&bcur[tid], c) : 0;
  }
  __syncthreads();
  for (int idx = tid; idx < NBUCK * SLOTS; idx += 256) {
    int b = idx / SLOTS, sl = idx - b * SLOTS;
    if (sl < scnt[b]) stage[sbase[b] + sl] = sbuf[b][sl];
  }
}

// ------- degscan: per-bucket hist + scan -> packed rowptr, dinv --------
__global__ __launch_bounds__(256) void degscan_kernel(const int* __restrict__ stage,
                                                      const int* __restrict__ bcur,
                                                      int* __restrict__ rowptr,
                                                      float* __restrict__ dinv,
                                                      int N, int cap) {
  __shared__ int h[BWID];
  __shared__ int ps[256];
  const int b = blockIdx.x;
  const int tid = threadIdx.x;
  h[tid] = 0;
  h[tid + 256] = 0;
  __syncthreads();
  const int lo = b * cap, hi = bcur[b];
  for (int i = lo + tid; i < hi; i += 256)
    atomicAdd(&h[(unsigned)stage[i] >> 17], 1);
  __syncthreads();
  const int a0 = h[2 * tid], a1 = h[2 * tid + 1];
  ps[tid] = a0 + a1;
  __syncthreads();
  for (int off = 1; off < 256; off <<= 1) {
    int v = (tid >= off) ? ps[tid - off] : 0;
    __syncthreads();
    ps[tid] += v;
    __syncthreads();
  }
  const int excl = ps[tid] - (a0 + a1);
  const int n0 = b << BSHIFT;
  const int na = n0 + 2 * tid;
  const int nb2 = na + 1;
  if (na < N) {
    rowptr[na] = (lo + excl) | (min(a0, 1023) << 22);
    dinv[na] = rsqrtf((float)(a0 + 1));
  }
  if (nb2 < N) {
    rowptr[nb2] = (lo + excl + a0) | (min(a1, 1023) << 22);
    dinv[nb2] = rsqrtf((float)(a1 + 1));
  }
}

// ---------------- phase-2 fill: per-bucket LDS-cursor scatter ----------------
__global__ __launch_bounds__(512) void fill2_kernel(const int* __restrict__ stage,
                                                    const int* __restrict__ bcur,
                                                    const int* __restrict__ rowptr,
                                                    const float* __restrict__ dinv,
                                                    int2* __restrict__ colw, int N,
                                                    int cap) {
  __shared__ int lcur[BWID];
  const int b = blockIdx.x;
  const int tid = threadIdx.x;
  const int n0 = b << BSHIFT;
  if (tid < BWID) {
    int node = n0 + tid;
    lcur[tid] = (node < N) ? (rowptr[node] & RPMASK) : 0;
  }
  __syncthreads();
  const int lo = b * cap, hi = bcur[b];
  for (int i = lo + tid; i < hi; i += 512) {
    int pk = stage[i];
    int s = pk & SMASK;
    int dl = (unsigned)pk >> 17;
    int slot = atomicAdd(&lcur[dl], 1);
    colw[slot] = make_int2(s, __float_as_int(dinv[s] * dinv[n0 + dl]));
  }
}

// ---------------- fallback path (small ws): direct atomics + scans ----------------
__global__ void detect64_kernel(const int* __restrict__ ei, int* __restrict__ flag) {
  int lane = threadIdx.x;
  int v = ei[2 * lane + 1];
  unsigned long long nz = __ballot(v != 0);
  if (lane == 0) *flag = (nz == 0ull) ? 1 : 0;
}
__global__ __launch_bounds__(256) void deg_atomic_kernel(const int* __restrict__ ei, int E,
                                                         const int* __restrict__ flag,
                                                         int* __restrict__ deg) {
  int e = blockIdx.x * 256 + threadIdx.x;
  if (e >= E) return;
  const int is64 = *flag;
  int d = is64 ? ei[2 * (E + e)] : ei[E + e];
  atomicAdd(&deg[d], 1);
}
__global__ __launch_bounds__(256) void dinv_kernel(const int* __restrict__ deg,
                                                   float* __restrict__ dinv, int N) {
  int i = blockIdx.x * 256 + threadIdx.x;
  if (i < N) dinv[i] = rsqrtf((float)(deg[i] + 1));
}
__global__ __launch_bounds__(1024) void scan1_kernel(const int* __restrict__ deg,
                                                     int* __restrict__ tmp,
                                                     int* __restrict__ partial, int N) {
  __shared__ int lds[1024];
  int i = blockIdx.x * 1024 + threadIdx.x;
  int v = (i < N) ? deg[i] : 0;
  lds[threadIdx.x] = v;
  __syncthreads();
  for (int off = 1; off < 1024; off <<= 1) {
    int t = (threadIdx.x >= (unsigned)off) ? lds[threadIdx.x - off] : 0;
    __syncthreads();
    lds[threadIdx.x] += t;
    __syncthreads();
  }
  if (i < N) tmp[i] = lds[threadIdx.x];  // inclusive within block
  if (threadIdx.x == 1023) partial[blockIdx.x] = lds[1023];
}
__global__ __launch_bounds__(128) void scan2_kernel(int* __restrict__ partial, int B) {
  __shared__ int lds[128];
  int t = threadIdx.x;
  int v = (t < B) ? partial[t] : 0;
  lds[t] = v;
  __syncthreads();
  for (int off = 1; off < 128; off <<= 1) {
    int tv = (t >= off) ? lds[t - off] : 0;
    __syncthreads();
    lds[t] += tv;
    __syncthreads();
  }
  if (t < B) partial[t] = lds[t] - v;  // exclusive
}
__global__ __launch_bounds__(1024) void scan3_kernel(const int* __restrict__ deg,
                                                     const int* __restrict__ tmp,
                                                     const int* __restrict__ partial,
                                                     int* __restrict__ rowptr,
                                                     int* __restrict__ cursor, int N) {
  int i = blockIdx.x * 1024 + threadIdx.x;
  if (i < N) {
    int d = deg[i];
    int start = tmp[i] + partial[blockIdx.x] - d;  // exclusive
    rowptr[i] = start | (min(d, 1023) << 22);
    cursor[i] = start;
  }
}
__global__ __launch_bounds__(256) void fill_direct_kernel(const int* __restrict__ ei, int E,
                                                          const int* __restrict__ flag,
                                                          const float* __restrict__ dinv,
                                                          int* __restrict__ cursor,
                                                          int2* __restrict__ colw) {
  int e = blockIdx.x * 256 + threadIdx.x;
  if (e >= E) return;
  const int is64 = *flag;
  int s = is64 ? ei[2 * e] : ei[e];
  int d = is64 ? ei[2 * (E + e)] : ei[E + e];
  int slot = atomicAdd(&cursor[d], 1);
  colw[slot] = make_int2(s, __float_as_int(dinv[s] * dinv[d]));
}

// ---------------- cast f32 -> bf16 table ----------------
__global__ __launch_bounds__(256) void cast_kernel(const float* __restrict__ in,
                                                   ushort* __restrict__ out, int total) {
  int i = (blockIdx.x * 256 + threadIdx.x) * 4;
  if (i >= total) return;
  float4 v = *(const float4*)(in + i);
  ushort4 o;
  o.x = f2bf_bits(v.x);
  o.y = f2bf_bits(v.y);
  o.z = f2bf_bits(v.z);
  o.w = f2bf_bits(v.w);
  *(ushort4*)(out + i) = o;
}

// ---------------- bnrelu: in-place T <- relu(a*T + c) ----------------
__global__ __launch_bounds__(256) void bnrelu_kernel(ushort* __restrict__ T,
                                                     const float* __restrict__ stats,
                                                     const float* __restrict__ g,
                                                     const float* __restrict__ be,
                                                     int N) {
  __shared__ float sa[FD], sc[FD];
  if (threadIdx.x < FD) {
    const float invN = 1.0f / (float)N;
    float m = stats[threadIdx.x] * invN;
    float v = stats[FD + threadIdx.x] * invN - m * m;
    float r = rsqrtf(v + EPSF);
    float a = g[threadIdx.x] * r;
    sa[threadIdx.x] = a;
    sc[threadIdx.x] = be[threadIdx.x] - m * a;
  }
  __syncthreads();
  const int idx = (blockIdx.x * 256 + threadIdx.x) * 8;  // ushort units
  if (idx >= N * FD) return;
  const int f0 = idx & (FD - 1);
  uint4 v = *(const uint4*)(T + idx);
  float h0 = __uint_as_float(v.x << 16);
  float h1 = __uint_as_float(v.x & 0xffff0000u);
  float h2 = __uint_as_float(v.y << 16);
  float h3 = __uint_as_float(v.y & 0xffff0000u);
  float h4 = __uint_as_float(v.z << 16);
  float h5 = __uint_as_float(v.z & 0xffff0000u);
  float h6 = __uint_as_float(v.w << 16);
  float h7 = __uint_as_float(v.w & 0xffff0000u);
  h0 = fmaxf(fmaf(sa[f0 + 0], h0, sc[f0 + 0]), 0.f);
  h1 = fmaxf(fmaf(sa[f0 + 1], h1, sc[f0 + 1]), 0.f);
  h2 = fmaxf(fmaf(sa[f0 + 2], h2, sc[f0 + 2]), 0.f);
  h3 = fmaxf(fmaf(sa[f0 + 3], h3, sc[f0 + 3]), 0.f);
  h4 = fmaxf(fmaf(sa[f0 + 4], h4, sc[f0 + 4]), 0.f);
  h5 = fmaxf(fmaf(sa[f0 + 5], h5, sc[f0 + 5]), 0.f);
  h6 = fmaxf(fmaf(sa[f0 + 6], h6, sc[f0 + 6]), 0.f);
  h7 = fmaxf(fmaf(sa[f0 + 7], h7, sc[f0 + 7]), 0.f);
  uint4 o;
  o.x = packbf(h0, h1);
  o.y = packbf(h2, h3);
  o.z = packbf(h4, h5);
  o.w = packbf(h6, h7);
  *(uint4*)(T + idx) = o;
}

// ---------------- fused agg + GEMM -------------------------------------------
// Block = 16 dsts = one GEMM tile. Phase 1 (agg): 4 waves x 4 dsts, gather-sum
// into registers, write 16x64 bf16 tile to LDS (padded rows). Phase 2 (MFMA):
// each wave multiplies the tile by its 16-col W-slice; epilogue = bias + store
// (+BN stats for BF16OUT). Out never round-trips through global as bf16 input.
template <bool BF16OUT>
__global__ __launch_bounds__(256) void fusedagg_kernel(
    const ushort* __restrict__ H, const int* __restrict__ rowptr,
    const int2* __restrict__ colw, const float* __restrict__ dinv,
    const float* __restrict__ W, const float* __restrict__ bias,
    ushort* __restrict__ outb, float* __restrict__ outf,
    float* __restrict__ stats, int N) {
  __shared__ ushort atile[16][72];  // 16 rows x 64 feat, padded to 72 (banks)
  __shared__ float sred[128];
  const int tid = threadIdx.x;
  const int lane = tid & 63;
  const int wid = tid >> 6;
  const int lo = lane & 15;
  const int hi = lane >> 4;
  if (BF16OUT && tid < 128) sred[tid] = 0.f;

  // W fragments for this wave's 16-col slice (hidden under agg latency)
  bf16x8 bfrag[2];
#pragma unroll
  for (int kk = 0; kk < 2; ++kk)
#pragma unroll
    for (int j = 0; j < 8; ++j) {
      int k = kk * 32 + hi * 8 + j;
      bfrag[kk][j] = (short)f2bf_bits(W[k * FD + wid * 16 + lo]);
    }
  const float bl = bias[wid * 16 + lo];

  // ---- phase 1: aggregation (R13 agg body) ----
  const int grp = hi;               // 0..3: dst group
  const int sg = (lane >> 3) & 1;   // subgroup: edge parity
  const int fl8 = lane & 7;         // feature block
  const int row0 = blockIdx.x * 16;
  const int dst = row0 + wid * 4 + grp;
  const bool live = dst < N;
  const int dc = live ? dst : N - 1;

  const unsigned rp = (unsigned)rowptr[dc];
  const int e0 = (int)(rp & RPMASK);
  const int e1 = live ? e0 + (int)(rp >> 22) : e0;

  float acc[4][8];
#pragma unroll
  for (int u = 0; u < 4; ++u)
#pragma unroll
    for (int j = 0; j < 8; ++j) acc[u][j] = 0.f;

  for (int base = e0; __any(base < e1); base += 8) {
#pragma unroll
    for (int u = 0; u < 4; ++u) {
      const int ee = base + 2 * u + sg;
      const bool valid = ee < e1;
      const int idx = valid ? ee : 0;
      const int2 cw = colw[idx];
      const float w = valid ? __int_as_float(cw.y) : 0.f;
      const uint4 uv = *(const uint4*)(H + (size_t)cw.x * FD + fl8 * 8);
      acc[u][0] = fmaf(w, __uint_as_float(uv.x << 16), acc[u][0]);
      acc[u][1] = fmaf(w, __uint_as_float(uv.x & 0xffff0000u), acc[u][1]);
      acc[u][2] = fmaf(w, __uint_as_float(uv.y << 16), acc[u][2]);
      acc[u][3] = fmaf(w, __uint_as_float(uv.y & 0xffff0000u), acc[u][3]);
      acc[u][4] = fmaf(w, __uint_as_float(uv.z << 16), acc[u][4]);
      acc[u][5] = fmaf(w, __uint_as_float(uv.z & 0xffff0000u), acc[u][5]);
      acc[u][6] = fmaf(w, __uint_as_float(uv.w << 16), acc[u][6]);
      acc[u][7] = fmaf(w, __uint_as_float(uv.w & 0xffff0000u), acc[u][7]);
    }
  }

  float r[8];
#pragma unroll
  for (int j = 0; j < 8; ++j)
    r[j] = (acc[0][j] + acc[1][j]) + (acc[2][j] + acc[3][j]);
#pragma unroll
  for (int j = 0; j < 8; ++j) r[j] += __shfl_xor(r[j], 8);

  // self-loop term
  const float di = dinv[dc];
  const float dsq = di * di;
  const uint4 sv = *(const uint4*)(H + (size_t)dc * FD + fl8 * 8);
  r[0] = fmaf(dsq, __uint_as_float(sv.x << 16), r[0]);
  r[1] = fmaf(dsq, __uint_as_float(sv.x & 0xffff0000u), r[1]);
  r[2] = fmaf(dsq, __uint_as_float(sv.y << 16), r[2]);
  r[3] = fmaf(dsq, __uint_as_float(sv.y & 0xffff0000u), r[3]);
  r[4] = fmaf(dsq, __uint_as_float(sv.z << 16), r[4]);
  r[5] = fmaf(dsq, __uint_as_float(sv.z & 0xffff0000u), r[5]);
  r[6] = fmaf(dsq, __uint_as_float(sv.w << 16), r[6]);
  r[7] = fmaf(dsq, __uint_as_float(sv.w & 0xffff0000u), r[7]);

  if (sg == 0) {
    const int dl = wid * 4 + grp;  // local row 0..15
    uint4 o;
    if (live) {
      o.x = packbf(r[0], r[1]);
      o.y = packbf(r[2], r[3]);
      o.z = packbf(r[4], r[5]);
      o.w = packbf(r[6], r[7]);
    } else {
      o = make_uint4(0u, 0u, 0u, 0u);
    }
    *(uint4*)&atile[dl][fl8 * 8] = o;
  }
  __syncthreads();

  // ---- phase 2: MFMA (A from LDS; m=lo row, k=hi*8+j / +32) ----
  bf16x8 a0 = *(const bf16x8*)&atile[lo][hi * 8];
  bf16x8 a1 = *(const bf16x8*)&atile[lo][hi * 8 + 32];
  f32x4 oacc = {0.f, 0.f, 0.f, 0.f};
  oacc = __builtin_amdgcn_mfma_f32_16x16x32_bf16(a0, bfrag[0], oacc, 0, 0, 0);
  oacc = __builtin_amdgcn_mfma_f32_16x16x32_bf16(a1, bfrag[1], oacc, 0, 0, 0);

  float s1 = 0.f, s2 = 0.f;
#pragma unroll
  for (int rg = 0; rg < 4; ++rg) {
    int row = row0 + hi * 4 + rg;
    if (row < N) {
      float o = oacc[rg] + bl;
      if (BF16OUT) {
        outb[(size_t)row * FD + wid * 16 + lo] = f2bf_bits(o);
        s1 += o;
        s2 += o * o;
      } else {
        outf[(size_t)row * FD + wid * 16 + lo] = o;
      }
    }
  }
  if (BF16OUT) {
    atomicAdd(&sred[wid * 16 + lo], s1);
    atomicAdd(&sred[64 + wid * 16 + lo], s2);
    __syncthreads();
    if (tid < 128) atomicAdd(&stats[tid], sred[tid]);
  }
}

extern "C" void kernel_launch(void* const* d_in, const int* in_sizes, int n_in,
                              void* d_out, int out_size, void* d_ws, size_t ws_size,
                              hipStream_t stream) {
  const float* x = (const float*)d_in[0];
  const int* ei = (const int*)d_in[1];
  const float* W1 = (const float*)d_in[2];
  const float* b1 = (const float*)d_in[3];
  const float* g1 = (const float*)d_in[4];
  const float* be1 = (const float*)d_in[5];
  const float* W2 = (const float*)d_in[6];
  const float* b2 = (const float*)d_in[7];
  const float* g2 = (const float*)d_in[8];
  const float* be2 = (const float*)d_in[9];
  const float* W3 = (const float*)d_in[10];
  const float* b3 = (const float*)d_in[11];

  const int N = in_sizes[0] / FD;
  const int E = in_sizes[1] / 2;
  const int nB = (N + BWID - 1) >> BSHIFT;  // used buckets
  const int cap = E / nB + 1024;            // fixed bucket capacity

  char* p = (char*)d_ws;
  auto alloc = [&](size_t bytes) {
    char* r = p;
    p += (bytes + 255) & ~(size_t)255;
    return r;
  };
  float* stats1 = (float*)alloc(128 * 4);
  float* stats2 = (float*)alloc(128 * 4);
  int* flag = (int*)alloc(4);
  int* partial = (int*)alloc(128 * 4);
  int* bcur = (int*)alloc(NBUCK * 4);
  int* deg = (int*)alloc((size_t)N * 4);
  int* tmp = (int*)alloc((size_t)N * 4);
  float* dinv = (float*)alloc((size_t)N * 4);
  int* rowptr = (int*)alloc((size_t)(N + 1) * 4);
  int* cursor = (int*)alloc((size_t)N * 4);
  int2* colw = (int2*)alloc((size_t)nB * cap * 8);
  ushort* TA = (ushort*)alloc((size_t)N * FD * 2);
  ushort* TB = (ushort*)alloc((size_t)N * FD * 2);
  int* stage = (int*)alloc((size_t)nB * cap * 4);  // packed 4B entries
  size_t full_need = (size_t)(p - (char*)d_ws);
  const bool two_phase =
      ((ws_size == 0) || (ws_size >= full_need)) && (N <= NBUCK * BWID) &&
      (N <= (1 << 17)) && ((size_t)nB * cap < (1u << 22));

  const int NB = (N + 1023) / 1024;
  const int EB = (E + P1_EDGES - 1) / P1_EDGES;

  if (two_phase) {
    init_kernel<<<1, 256, 0, stream>>>(bcur, stats1, stats2, nB, cap);
    fill1_kernel<<<EB, 256, 0, stream>>>(ei, E, bcur, stage);
    degscan_kernel<<<nB, 256, 0, stream>>>(stage, bcur, rowptr, dinv, N, cap);
    fill2_kernel<<<nB, 512, 0, stream>>>(stage, bcur, rowptr, dinv, colw, N, cap);
  } else {
    hipMemsetAsync(deg, 0, (size_t)N * 4, stream);
    hipMemsetAsync(stats1, 0, 128 * 4, stream);
    hipMemsetAsync(stats2, 0, 128 * 4, stream);
    detect64_kernel<<<1, 64, 0, stream>>>(ei, flag);
    deg_atomic_kernel<<<(E + 255) / 256, 256, 0, stream>>>(ei, E, flag, deg);
    dinv_kernel<<<(N + 255) / 256, 256, 0, stream>>>(deg, dinv, N);
    scan1_kernel<<<NB, 1024, 0, stream>>>(deg, tmp, partial, N);
    scan2_kernel<<<1, 128, 0, stream>>>(partial, NB);
    scan3_kernel<<<NB, 1024, 0, stream>>>(deg, tmp, partial, rowptr, cursor, N);
    fill_direct_kernel<<<(E + 255) / 256, 256, 0, stream>>>(ei, E, flag, dinv, cursor,
                                                            colw);
  }

  const int fusedGrid = (N + 15) / 16;  // 16 dsts = 1 tile per block
  const int castGrid = (N * FD / 4 + 255) / 256;
  const int bnGrid = (N * FD / 8 + 255) / 256;

  // layer 1: cast(x)->TA ; fused agg+gemm: TA -> TB (+stats1)
  cast_kernel<<<castGrid, 256, 0, stream>>>(x, TA, N * FD);
  fusedagg_kernel<true><<<fusedGrid, 256, 0, stream>>>(TA, rowptr, colw, dinv, W1, b1,
                                                       TB, nullptr, stats1, N);
  // layer 2: bnrelu(TB) ; fused: TB -> TA (+stats2)
  bnrelu_kernel<<<bnGrid, 256, 0, stream>>>(TB, stats1, g1, be1, N);
  fusedagg_kernel<true><<<fusedGrid, 256, 0, stream>>>(TB, rowptr, colw, dinv, W2, b2,
                                                       TA, nullptr, stats2, N);
  // layer 3: bnrelu(TA) ; fused: TA -> d_out (f32)
  bnrelu_kernel<<<bnGrid, 256, 0, stream>>>(TA, stats2, g2, be2, N);
  fusedagg_kernel<false><<<fusedGrid, 256, 0, stream>>>(TA, rowptr, colw, dinv, W3, b3,
                                                        nullptr, (float*)d_out, nullptr,
                                                        N);
}

// Round 15
// 285.314 us; speedup vs baseline: 1.6659x; 1.6659x over previous
//
#include <hip/hip_runtime.h>
#include <hip/hip_bf16.h>

// GCN 3-layer fused pipeline for MI355X.
// Â(xW) == (Âx)W ; CSR built per call; BN+ReLU as separate in-place pass.
// R15: consolidate. R13 structure (unfused agg + MFMA gemm; identity order;
//      fixed-cap buckets, packed rowptr) + R14's 4B-packed stage entries.
//      Fusion/perm/unroll16/dot2 all measured-regressed and are reverted.

#define FD 64
#define EPSF 1e-5f

#define NBUCK 256        // max buckets (bucket = dst >> BSHIFT)
#define BSHIFT 9
#define BWID 512         // nodes per bucket (pow2); supports N <= 131072
#define SLOTS 28         // LDS slots per bucket in fill1
#define P1_EDGES 4096
#define RPMASK 0x3FFFFF  // rowptr start mask (22 bits); deg in bits 22..31
#define SMASK 0x1FFFF    // packed stage: src in 17 bits, dlocal in bits 17..25

typedef __attribute__((ext_vector_type(8))) short bf16x8;
typedef __attribute__((ext_vector_type(4))) float f32x4;

__device__ __forceinline__ ushort f2bf_bits(float f) {
  __hip_bfloat16 h = __float2bfloat16(f);
  return *(ushort*)&h;
}
__device__ __forceinline__ unsigned packbf(float lo, float hi) {
  return (unsigned)f2bf_bits(lo) | ((unsigned)f2bf_bits(hi) << 16);
}

// ---------------- init: bcur = b*cap, zero stats ----------------
__global__ __launch_bounds__(256) void init_kernel(int* __restrict__ bcur,
                                                   float* __restrict__ stats1,
                                                   float* __restrict__ stats2,
                                                   int nB, int cap) {
  int t = threadIdx.x;
  if (t < nB) bcur[t] = t * cap;
  if (t < 128) {
    stats1[t] = 0.f;
    stats2[t] = 0.f;
  }
}

// ---------------- phase-1 fill: LDS-binned staging, packed 4B entries --------
__global__ __launch_bounds__(256) void fill1_kernel(const int* __restrict__ ei, int E,
                                                    int* __restrict__ bcur,
                                                    int* __restrict__ stage) {
  __shared__ int sbuf[NBUCK][SLOTS];
  __shared__ int scnt[NBUCK];
  __shared__ int sbase[NBUCK];
  __shared__ int s_is64;
  const int tid = threadIdx.x;
  scnt[tid] = 0;
  if (tid < 64) {
    int v = ei[2 * tid + 1];
    unsigned long long nz = __ballot(v != 0);
    if (tid == 0) s_is64 = (nz == 0ull) ? 1 : 0;
  }
  __syncthreads();
  const int is64 = s_is64;
  const int base = blockIdx.x * P1_EDGES;
#pragma unroll 1
  for (int k = 0; k < P1_EDGES / 256; ++k) {
    int e = base + k * 256 + tid;
    if (e < E) {
      int s = is64 ? ei[2 * e] : ei[e];
      int d = is64 ? ei[2 * (E + e)] : ei[E + e];
      int b = d >> BSHIFT;
      int pk = s | ((d & (BWID - 1)) << 17);
      int pos = atomicAdd(&scnt[b], 1);
      if (pos < SLOTS) {
        sbuf[b][pos] = pk;
      } else {
        stage[atomicAdd(&bcur[b], 1)] = pk;  // rare overflow
      }
    }
  }
  __syncthreads();
  {
    int c = scnt[tid];
    if (c > SLOTS) c = SLOTS;
    scnt[tid] = c;
    sbase[tid] = c ? atomicAdd(&bcur[tid], c) : 0;
  }
  __syncthreads();
  for (int idx = tid; idx < NBUCK * SLOTS; idx += 256) {
    int b = idx / SLOTS, sl = idx - b * SLOTS;
    if (sl < scnt[b]) stage[sbase[b] + sl] = sbuf[b][sl];
  }
}

// ------- degscan: per-bucket hist + scan -> packed rowptr, dinv --------
__global__ __launch_bounds__(256) void degscan_kernel(const int* __restrict__ stage,
                                                      const int* __restrict__ bcur,
                                                      int* __restrict__ rowptr,
                                                      float* __restrict__ dinv,
                                                      int N, int cap) {
  __shared__ int h[BWID];
  __shared__ int ps[256];
  const int b = blockIdx.x;
  const int tid = threadIdx.x;
  h[tid] = 0;
  h[tid + 256] = 0;
  __syncthreads();
  const int lo = b * cap, hi = bcur[b];
  for (int i = lo + tid; i < hi; i += 256)
    atomicAdd(&h[(unsigned)stage[i] >> 17], 1);
  __syncthreads();
  const int a0 = h[2 * tid], a1 = h[2 * tid + 1];
  ps[tid] = a0 + a1;
  __syncthreads();
  for (int off = 1; off < 256; off <<= 1) {
    int v = (tid >= off) ? ps[tid - off] : 0;
    __syncthreads();
    ps[tid] += v;
    __syncthreads();
  }
  const int excl = ps[tid] - (a0 + a1);
  const int n0 = b << BSHIFT;
  const int na = n0 + 2 * tid;
  const int nb2 = na + 1;
  if (na < N) {
    rowptr[na] = (lo + excl) | (min(a0, 1023) << 22);
    dinv[na] = rsqrtf((float)(a0 + 1));
  }
  if (nb2 < N) {
    rowptr[nb2] = (lo + excl + a0) | (min(a1, 1023) << 22);
    dinv[nb2] = rsqrtf((float)(a1 + 1));
  }
}

// ---------------- phase-2 fill: per-bucket LDS-cursor scatter ----------------
__global__ __launch_bounds__(512) void fill2_kernel(const int* __restrict__ stage,
                                                    const int* __restrict__ bcur,
                                                    const int* __restrict__ rowptr,
                                                    const float* __restrict__ dinv,
                                                    int2* __restrict__ colw, int N,
                                                    int cap) {
  __shared__ int lcur[BWID];
  const int b = blockIdx.x;
  const int tid = threadIdx.x;
  const int n0 = b << BSHIFT;
  if (tid < BWID) {
    int node = n0 + tid;
    lcur[tid] = (node < N) ? (rowptr[node] & RPMASK) : 0;
  }
  __syncthreads();
  const int lo = b * cap, hi = bcur[b];
  for (int i = lo + tid; i < hi; i += 512) {
    int pk = stage[i];
    int s = pk & SMASK;
    int dl = (unsigned)pk >> 17;
    int slot = atomicAdd(&lcur[dl], 1);
    colw[slot] = make_int2(s, __float_as_int(dinv[s] * dinv[n0 + dl]));
  }
}

// ---------------- fallback path (small ws): direct atomics + scans ----------------
__global__ void detect64_kernel(const int* __restrict__ ei, int* __restrict__ flag) {
  int lane = threadIdx.x;
  int v = ei[2 * lane + 1];
  unsigned long long nz = __ballot(v != 0);
  if (lane == 0) *flag = (nz == 0ull) ? 1 : 0;
}
__global__ __launch_bounds__(256) void deg_atomic_kernel(const int* __restrict__ ei, int E,
                                                         const int* __restrict__ flag,
                                                         int* __restrict__ deg) {
  int e = blockIdx.x * 256 + threadIdx.x;
  if (e >= E) return;
  const int is64 = *flag;
  int d = is64 ? ei[2 * (E + e)] : ei[E + e];
  atomicAdd(&deg[d], 1);
}
__global__ __launch_bounds__(256) void dinv_kernel(const int* __restrict__ deg,
                                                   float* __restrict__ dinv, int N) {
  int i = blockIdx.x * 256 + threadIdx.x;
  if (i < N) dinv[i] = rsqrtf((float)(deg[i] + 1));
}
__global__ __launch_bounds__(1024) void scan1_kernel(const int* __restrict__ deg,
                                                     int* __restrict__ tmp,
                                                     int* __restrict__ partial, int N) {
  __shared__ int lds[1024];
  int i = blockIdx.x * 1024 + threadIdx.x;
  int v = (i < N) ? deg[i] : 0;
  lds[threadIdx.x] = v;
  __syncthreads();
  for (int off = 1; off < 1024; off <<= 1) {
    int t = (threadIdx.x >= (unsigned)off) ? lds[threadIdx.x - off] : 0;
    __syncthreads();
    lds[threadIdx.x] += t;
    __syncthreads();
  }
  if (i < N) tmp[i] = lds[threadIdx.x];  // inclusive within block
  if (threadIdx.x == 1023) partial[blockIdx.x] = lds[1023];
}
__global__ __launch_bounds__(128) void scan2_kernel(int* __restrict__ partial, int B) {
  __shared__ int lds[128];
  int t = threadIdx.x;
  int v = (t < B) ? partial[t] : 0;
  lds[t] = v;
  __syncthreads();
  for (int off = 1; off < 128; off <<= 1) {
    int tv = (t >= off) ? lds[t - off] : 0;
    __syncthreads();
    lds[t] += tv;
    __syncthreads();
  }
  if (t < B) partial[t] = lds[t] - v;  // exclusive
}
__global__ __launch_bounds__(1024) void scan3_kernel(const int* __restrict__ deg,
                                                     const int* __restrict__ tmp,
                                                     const int* __restrict__ partial,
                                                     int* __restrict__ rowptr,
                                                     int* __restrict__ cursor, int N) {
  int i = blockIdx.x * 1024 + threadIdx.x;
  if (i < N) {
    int d = deg[i];
    int start = tmp[i] + partial[blockIdx.x] - d;  // exclusive
    rowptr[i] = start | (min(d, 1023) << 22);
    cursor[i] = start;
  }
}
__global__ __launch_bounds__(256) void fill_direct_kernel(const int* __restrict__ ei, int E,
                                                          const int* __restrict__ flag,
                                                          const float* __restrict__ dinv,
                                                          int* __restrict__ cursor,
                                                          int2* __restrict__ colw) {
  int e = blockIdx.x * 256 + threadIdx.x;
  if (e >= E) return;
  const int is64 = *flag;
  int s = is64 ? ei[2 * e] : ei[e];
  int d = is64 ? ei[2 * (E + e)] : ei[E + e];
  int slot = atomicAdd(&cursor[d], 1);
  colw[slot] = make_int2(s, __float_as_int(dinv[s] * dinv[d]));
}

// ---------------- cast f32 -> bf16 table ----------------
__global__ __launch_bounds__(256) void cast_kernel(const float* __restrict__ in,
                                                   ushort* __restrict__ out, int total) {
  int i = (blockIdx.x * 256 + threadIdx.x) * 4;
  if (i >= total) return;
  float4 v = *(const float4*)(in + i);
  ushort4 o;
  o.x = f2bf_bits(v.x);
  o.y = f2bf_bits(v.y);
  o.z = f2bf_bits(v.z);
  o.w = f2bf_bits(v.w);
  *(ushort4*)(out + i) = o;
}

// ---------------- bnrelu: in-place T <- relu(a*T + c) ----------------
__global__ __launch_bounds__(256) void bnrelu_kernel(ushort* __restrict__ T,
                                                     const float* __restrict__ stats,
                                                     const float* __restrict__ g,
                                                     const float* __restrict__ be,
                                                     int N) {
  __shared__ float sa[FD], sc[FD];
  if (threadIdx.x < FD) {
    const float invN = 1.0f / (float)N;
    float m = stats[threadIdx.x] * invN;
    float v = stats[FD + threadIdx.x] * invN - m * m;
    float r = rsqrtf(v + EPSF);
    float a = g[threadIdx.x] * r;
    sa[threadIdx.x] = a;
    sc[threadIdx.x] = be[threadIdx.x] - m * a;
  }
  __syncthreads();
  const int idx = (blockIdx.x * 256 + threadIdx.x) * 8;  // ushort units
  if (idx >= N * FD) return;
  const int f0 = idx & (FD - 1);
  uint4 v = *(const uint4*)(T + idx);
  float h0 = __uint_as_float(v.x << 16);
  float h1 = __uint_as_float(v.x & 0xffff0000u);
  float h2 = __uint_as_float(v.y << 16);
  float h3 = __uint_as_float(v.y & 0xffff0000u);
  float h4 = __uint_as_float(v.z << 16);
  float h5 = __uint_as_float(v.z & 0xffff0000u);
  float h6 = __uint_as_float(v.w << 16);
  float h7 = __uint_as_float(v.w & 0xffff0000u);
  h0 = fmaxf(fmaf(sa[f0 + 0], h0, sc[f0 + 0]), 0.f);
  h1 = fmaxf(fmaf(sa[f0 + 1], h1, sc[f0 + 1]), 0.f);
  h2 = fmaxf(fmaf(sa[f0 + 2], h2, sc[f0 + 2]), 0.f);
  h3 = fmaxf(fmaf(sa[f0 + 3], h3, sc[f0 + 3]), 0.f);
  h4 = fmaxf(fmaf(sa[f0 + 4], h4, sc[f0 + 4]), 0.f);
  h5 = fmaxf(fmaf(sa[f0 + 5], h5, sc[f0 + 5]), 0.f);
  h6 = fmaxf(fmaf(sa[f0 + 6], h6, sc[f0 + 6]), 0.f);
  h7 = fmaxf(fmaf(sa[f0 + 7], h7, sc[f0 + 7]), 0.f);
  uint4 o;
  o.x = packbf(h0, h1);
  o.y = packbf(h2, h3);
  o.z = packbf(h4, h5);
  o.w = packbf(h6, h7);
  *(uint4*)(T + idx) = o;
}

// ---------------- aggregation: identity-order weighted gather-sum ------------
// out[dst] = dinv[dst]^2 * H[dst] + sum_e w_e * H[src_e]
// Wave = 4 groups (16 lanes, one dst each); group = 2 subgroups (8 lanes,
// alternating edges); lane covers 8 features via uint4. 8 edges/step.
// Packed rowptr: start | deg<<22 (one load gives both bounds).
// NOTE: independent waves + identity order are load-bearing -- every
// reorder/couple attempt (R8 perm, R12 local perm, R14 fusion) regressed.
__global__ __launch_bounds__(256) void agg_kernel(const ushort* __restrict__ H,
                                                  const int* __restrict__ rowptr,
                                                  const int2* __restrict__ colw,
                                                  const float* __restrict__ dinv,
                                                  ushort* __restrict__ out, int N) {
  const int lane = threadIdx.x & 63;
  const int wid = threadIdx.x >> 6;
  const int grp = lane >> 4;        // 0..3: dst group
  const int sg = (lane >> 3) & 1;   // subgroup: edge parity
  const int fl8 = lane & 7;         // feature block: fl8*8 .. fl8*8+7
  const int dst = (blockIdx.x * 4 + wid) * 4 + grp;
  const bool live = dst < N;
  const int dc = live ? dst : N - 1;

  const unsigned rp = (unsigned)rowptr[dc];
  const int e0 = (int)(rp & RPMASK);
  const int e1 = live ? e0 + (int)(rp >> 22) : e0;

  float acc[4][8];
#pragma unroll
  for (int u = 0; u < 4; ++u)
#pragma unroll
    for (int j = 0; j < 8; ++j) acc[u][j] = 0.f;

  for (int base = e0; __any(base < e1); base += 8) {
#pragma unroll
    for (int u = 0; u < 4; ++u) {
      const int ee = base + 2 * u + sg;
      const bool valid = ee < e1;
      const int idx = valid ? ee : 0;
      const int2 cw = colw[idx];
      const float w = valid ? __int_as_float(cw.y) : 0.f;
      const uint4 uv = *(const uint4*)(H + (size_t)cw.x * FD + fl8 * 8);
      acc[u][0] = fmaf(w, __uint_as_float(uv.x << 16), acc[u][0]);
      acc[u][1] = fmaf(w, __uint_as_float(uv.x & 0xffff0000u), acc[u][1]);
      acc[u][2] = fmaf(w, __uint_as_float(uv.y << 16), acc[u][2]);
      acc[u][3] = fmaf(w, __uint_as_float(uv.y & 0xffff0000u), acc[u][3]);
      acc[u][4] = fmaf(w, __uint_as_float(uv.z << 16), acc[u][4]);
      acc[u][5] = fmaf(w, __uint_as_float(uv.z & 0xffff0000u), acc[u][5]);
      acc[u][6] = fmaf(w, __uint_as_float(uv.w << 16), acc[u][6]);
      acc[u][7] = fmaf(w, __uint_as_float(uv.w & 0xffff0000u), acc[u][7]);
    }
  }

  float r[8];
#pragma unroll
  for (int j = 0; j < 8; ++j)
    r[j] = (acc[0][j] + acc[1][j]) + (acc[2][j] + acc[3][j]);
#pragma unroll
  for (int j = 0; j < 8; ++j) r[j] += __shfl_xor(r[j], 8);

  // self-loop term
  const float di = dinv[dc];
  const float dsq = di * di;
  const uint4 sv = *(const uint4*)(H + (size_t)dc * FD + fl8 * 8);
  r[0] = fmaf(dsq, __uint_as_float(sv.x << 16), r[0]);
  r[1] = fmaf(dsq, __uint_as_float(sv.x & 0xffff0000u), r[1]);
  r[2] = fmaf(dsq, __uint_as_float(sv.y << 16), r[2]);
  r[3] = fmaf(dsq, __uint_as_float(sv.y & 0xffff0000u), r[3]);
  r[4] = fmaf(dsq, __uint_as_float(sv.z << 16), r[4]);
  r[5] = fmaf(dsq, __uint_as_float(sv.z & 0xffff0000u), r[5]);
  r[6] = fmaf(dsq, __uint_as_float(sv.w << 16), r[6]);
  r[7] = fmaf(dsq, __uint_as_float(sv.w & 0xffff0000u), r[7]);

  if (live && sg == 0) {
    uint4 o;
    o.x = packbf(r[0], r[1]);
    o.y = packbf(r[2], r[3]);
    o.z = packbf(r[4], r[5]);
    o.w = packbf(r[6], r[7]);
    *(uint4*)(out + (size_t)dst * FD + fl8 * 8) = o;
  }
}

// ---------------- MFMA GEMM: out = A(bf16) @ W + b -------------------------
template <bool BF16OUT>
__global__ __launch_bounds__(256) void gemm_mfma_kernel(const ushort* __restrict__ A,
                                                        const float* __restrict__ W,
                                                        const float* __restrict__ bias,
                                                        ushort* __restrict__ outb,
                                                        float* __restrict__ outf,
                                                        float* __restrict__ stats, int N) {
  const int lane = threadIdx.x & 63;
  const int wid = threadIdx.x >> 6;
  const int lo = lane & 15;
  const int hi = lane >> 4;

  __shared__ float sred[128];
  if (BF16OUT) {
    if (threadIdx.x < 128) sred[threadIdx.x] = 0.f;
    __syncthreads();
  }

  bf16x8 bfrag[2][4];
#pragma unroll
  for (int kk = 0; kk < 2; ++kk)
#pragma unroll
    for (int nt = 0; nt < 4; ++nt)
#pragma unroll
      for (int j = 0; j < 8; ++j) {
        int k = kk * 32 + hi * 8 + j;
        bfrag[kk][nt][j] = (short)f2bf_bits(W[k * FD + nt * 16 + lo]);
      }

  float bl[4];
#pragma unroll
  for (int nt = 0; nt < 4; ++nt) bl[nt] = bias[nt * 16 + lo];

  float s1[4] = {0.f, 0.f, 0.f, 0.f};
  float s2[4] = {0.f, 0.f, 0.f, 0.f};

  const int TILES = (N + 15) / 16;
  const int stride = gridDim.x * 4;
  for (int tile = blockIdx.x * 4 + wid; tile < TILES; tile += stride) {
    const int row0 = tile * 16;
    const int ar = min(row0 + lo, N - 1);
    const ushort* ap = A + (size_t)ar * FD + hi * 8;
    bf16x8 a0 = *(const bf16x8*)ap;
    bf16x8 a1 = *(const bf16x8*)(ap + 32);

    f32x4 acc[4] = {{0.f, 0.f, 0.f, 0.f},
                    {0.f, 0.f, 0.f, 0.f},
                    {0.f, 0.f, 0.f, 0.f},
                    {0.f, 0.f, 0.f, 0.f}};
#pragma unroll
    for (int nt = 0; nt < 4; ++nt) {
      acc[nt] = __builtin_amdgcn_mfma_f32_16x16x32_bf16(a0, bfrag[0][nt], acc[nt], 0, 0, 0);
      acc[nt] = __builtin_amdgcn_mfma_f32_16x16x32_bf16(a1, bfrag[1][nt], acc[nt], 0, 0, 0);
    }

#pragma unroll
    for (int nt = 0; nt < 4; ++nt) {
#pragma unroll
      for (int r = 0; r < 4; ++r) {
        int row = row0 + hi * 4 + r;
        if (row < N) {
          float o = acc[nt][r] + bl[nt];
          if (BF16OUT) {
            outb[(size_t)row * FD + nt * 16 + lo] = f2bf_bits(o);
            s1[nt] += o;
            s2[nt] += o * o;
          } else {
            outf[(size_t)row * FD + nt * 16 + lo] = o;
          }
        }
      }
    }
  }

  if (BF16OUT) {
#pragma unroll
    for (int nt = 0; nt < 4; ++nt) {
      atomicAdd(&sred[nt * 16 + lo], s1[nt]);
      atomicAdd(&sred[64 + nt * 16 + lo], s2[nt]);
    }
    __syncthreads();
    if (threadIdx.x < 128) atomicAdd(&stats[threadIdx.x], sred[threadIdx.x]);
  }
}

extern "C" void kernel_launch(void* const* d_in, const int* in_sizes, int n_in,
                              void* d_out, int out_size, void* d_ws, size_t ws_size,
                              hipStream_t stream) {
  const float* x = (const float*)d_in[0];
  const int* ei = (const int*)d_in[1];
  const float* W1 = (const float*)d_in[2];
  const float* b1 = (const float*)d_in[3];
  const float* g1 = (const float*)d_in[4];
  const float* be1 = (const float*)d_in[5];
  const float* W2 = (const float*)d_in[6];
  const float* b2 = (const float*)d_in[7];
  const float* g2 = (const float*)d_in[8];
  const float* be2 = (const float*)d_in[9];
  const float* W3 = (const float*)d_in[10];
  const float* b3 = (const float*)d_in[11];

  const int N = in_sizes[0] / FD;
  const int E = in_sizes[1] / 2;
  const int nB = (N + BWID - 1) >> BSHIFT;  // used buckets
  const int cap = E / nB + 1024;            // fixed bucket capacity

  char* p = (char*)d_ws;
  auto alloc = [&](size_t bytes) {
    char* r = p;
    p += (bytes + 255) & ~(size_t)255;
    return r;
  };
  float* stats1 = (float*)alloc(128 * 4);
  float* stats2 = (float*)alloc(128 * 4);
  int* flag = (int*)alloc(4);
  int* partial = (int*)alloc(128 * 4);
  int* bcur = (int*)alloc(NBUCK * 4);
  int* deg = (int*)alloc((size_t)N * 4);
  int* tmp = (int*)alloc((size_t)N * 4);
  float* dinv = (float*)alloc((size_t)N * 4);
  int* rowptr = (int*)alloc((size_t)(N + 1) * 4);
  int* cursor = (int*)alloc((size_t)N * 4);
  int2* colw = (int2*)alloc((size_t)nB * cap * 8);
  ushort* TA = (ushort*)alloc((size_t)N * FD * 2);
  ushort* TB = (ushort*)alloc((size_t)N * FD * 2);
  int* stage = (int*)alloc((size_t)nB * cap * 4);  // packed 4B entries
  size_t full_need = (size_t)(p - (char*)d_ws);
  const bool two_phase =
      ((ws_size == 0) || (ws_size >= full_need)) && (N <= NBUCK * BWID) &&
      (N <= (1 << 17)) && ((size_t)nB * cap < (1u << 22));

  const int NB = (N + 1023) / 1024;
  const int EB = (E + P1_EDGES - 1) / P1_EDGES;

  if (two_phase) {
    init_kernel<<<1, 256, 0, stream>>>(bcur, stats1, stats2, nB, cap);
    fill1_kernel<<<EB, 256, 0, stream>>>(ei, E, bcur, stage);
    degscan_kernel<<<nB, 256, 0, stream>>>(stage, bcur, rowptr, dinv, N, cap);
    fill2_kernel<<<nB, 512, 0, stream>>>(stage, bcur, rowptr, dinv, colw, N, cap);
  } else {
    hipMemsetAsync(deg, 0, (size_t)N * 4, stream);
    hipMemsetAsync(stats1, 0, 128 * 4, stream);
    hipMemsetAsync(stats2, 0, 128 * 4, stream);
    detect64_kernel<<<1, 64, 0, stream>>>(ei, flag);
    deg_atomic_kernel<<<(E + 255) / 256, 256, 0, stream>>>(ei, E, flag, deg);
    dinv_kernel<<<(N + 255) / 256, 256, 0, stream>>>(deg, dinv, N);
    scan1_kernel<<<NB, 1024, 0, stream>>>(deg, tmp, partial, N);
    scan2_kernel<<<1, 128, 0, stream>>>(partial, NB);
    scan3_kernel<<<NB, 1024, 0, stream>>>(deg, tmp, partial, rowptr, cursor, N);
    fill_direct_kernel<<<(E + 255) / 256, 256, 0, stream>>>(ei, E, flag, dinv, cursor,
                                                            colw);
  }

  const int aggGrid = (N + 15) / 16;  // 4 waves/block x 4 dst/wave
  const int castGrid = (N * FD / 4 + 255) / 256;
  const int bnGrid = (N * FD / 8 + 255) / 256;
  const int TILES = (N + 15) / 16;
  const int gemmGrid = (TILES + 7) / 8;  // 2 tiles/wave

  // layer 1
  cast_kernel<<<castGrid, 256, 0, stream>>>(x, TA, N * FD);
  agg_kernel<<<aggGrid, 256, 0, stream>>>(TA, rowptr, colw, dinv, TB, N);
  gemm_mfma_kernel<true><<<gemmGrid, 256, 0, stream>>>(TB, W1, b1, TA, nullptr, stats1, N);

  // layer 2
  bnrelu_kernel<<<bnGrid, 256, 0, stream>>>(TA, stats1, g1, be1, N);
  agg_kernel<<<aggGrid, 256, 0, stream>>>(TA, rowptr, colw, dinv, TB, N);
  gemm_mfma_kernel<true><<<gemmGrid, 256, 0, stream>>>(TB, W2, b2, TA, nullptr, stats2, N);

  // layer 3
  bnrelu_kernel<<<bnGrid, 256, 0, stream>>>(TA, stats2, g2, be2, N);
  agg_kernel<<<aggGrid, 256, 0, stream>>>(TA, rowptr, colw, dinv, TB, N);
  gemm_mfma_kernel<false><<<gemmGrid, 256, 0, stream>>>(TB, W3, b3, nullptr,
                                                        (float*)d_out, nullptr, N);
}